// Round 1
// baseline (576.353 us; speedup 1.0000x reference)
//
#include <hip/hip_runtime.h>
#include <hip/hip_bf16.h>

#define BB 4
#define DE 128
#define DO_ 512
#define THW 10240
#define HW 1024
#define SCALE 0.08838834764831845f      // 1/sqrt(128)
#define INV2S2 0.05555555555555555f     // 1/(2*3^2)
#define NCH 32
#define CHT 320                          // 10240 / 32

// ws layout (bytes):
//   amax  @ 0          : BB*THW ull packed (value,~idx) argmax   (327,680 B)
//   part  @ 327,680    : BB*NCH*HW*2 floats                      (1,048,576 B)
//   stats @ 1,376,256  : BB*HW*2 floats                          (32,768 B)
//   mo16  @ 1,409,024  : bf16 mo   [B][Do][THW]                  (41.94 MB)
//   pwT   @ 43,352,064 : bf16 pw^T [B][HW][THW]                  (83.89 MB)
// Total ws requirement: 127,238,144 bytes (~121.3 MiB) — unchanged.
#define WS_PART_F  81920
#define WS_STATS_F 344064
#define WS_MO16_B  1409024ull
#define WS_PWT_B   43352064ull

using bf16x8 = __attribute__((ext_vector_type(8))) short;
using f32x4  = __attribute__((ext_vector_type(4))) float;
using u16x8  = __attribute__((ext_vector_type(8))) unsigned short;

__device__ __forceinline__ unsigned short f2bf(float f) {
    __hip_bfloat16 h = __float2bfloat16(f);
    return *reinterpret_cast<unsigned short*>(&h);
}
__device__ __forceinline__ void glds16(const void* g, void* l) {
    __builtin_amdgcn_global_load_lds((const __attribute__((address_space(1))) void*)g,
                                     (__attribute__((address_space(3))) void*)l,
                                     16, 0, 0);
}
// monotone float->uint mapping (order-preserving for all finite floats)
__device__ __forceinline__ unsigned int ordf(float f) {
    unsigned int u = __float_as_uint(f);
    return (u & 0x80000000u) ? ~u : (u | 0x80000000u);
}

// ---------------- init: zero mem part of out, copy q_out part, zero amax ----------------
__global__ __launch_bounds__(256) void k_init(float* __restrict__ out,
                                              const float* __restrict__ qout,
                                              float4* __restrict__ amax4)
{
    int idx = blockIdx.x * 256 + threadIdx.x;
    if (idx < 20480) amax4[idx] = make_float4(0.f, 0.f, 0.f, 0.f);  // 327,680 B of amax
    int b  = idx >> 18;
    int r  = idx & 262143;
    int c  = r >> 8;
    int q4 = r & 255;
    float4* dst = (float4*)out + idx;
    if (c < DO_) {
        *dst = make_float4(0.f, 0.f, 0.f, 0.f);
    } else {
        const float4* src = (const float4*)qout + ((size_t)(b * DO_ + (c - DO_)) << 8) + q4;
        *dst = *src;
    }
}

// ---------------- GEMM1 (fp32) + fused row argmax ----------------
// 128x128 tile, 8x8 per thread, BK=32 chunks. Accumulation order per element is
// k=0..127 sequential fmaf — bit-identical to the previous passing kernel, so the
// argmax-sensitive values do not move.
// XCD slice swizzle: id%8 = tbg constant per (tb-group) → each XCD owns 10 tb-tiles
// x all 8 qb for each b → mi tile fetched by one XCD only (was 8x refetch).
__global__ __launch_bounds__(256) void k_gemm1(const float* __restrict__ mi,
                                               const float* __restrict__ qi,
                                               float* __restrict__ p,
                                               unsigned long long* __restrict__ amax)
{
    __shared__ float As[32][128];   // [k][t]
    __shared__ float Bs[32][128];   // [k][q]
    int id  = blockIdx.x;
    int tbg = id & 7;
    int rr  = id >> 3;              // [0,320)
    int b   = rr / 80;
    int j   = rr - b * 80;          // [0,80)
    int tb  = tbg * 10 + (j >> 3);  // [0,80)
    int qb  = j & 7;                // [0,8)
    int tid = threadIdx.x;
    int tx = tid & 15, ty = tid >> 4;
    int lane = tid & 63;

    const float* A  = mi + (size_t)b * DE * THW + (size_t)tb * 128;
    const float* Bq = qi + (size_t)b * DE * HW  + qb * 128;

    float acc[8][8] = {};
    for (int kc = 0; kc < 4; ++kc) {
        __syncthreads();
#pragma unroll
        for (int i = 0; i < 4; ++i) {
            int s  = tid + i * 256;
            int kl = s >> 5;
            int c4 = (s & 31) << 2;
            *(float4*)&As[kl][c4] = *(const float4*)&A [(size_t)(kc * 32 + kl) * THW + c4];
            *(float4*)&Bs[kl][c4] = *(const float4*)&Bq[(size_t)(kc * 32 + kl) * HW  + c4];
        }
        __syncthreads();
#pragma unroll 2
        for (int kl = 0; kl < 32; ++kl) {
            float4 a0 = *(float4*)&As[kl][ty * 8];
            float4 a1 = *(float4*)&As[kl][ty * 8 + 4];
            float4 b0 = *(float4*)&Bs[kl][tx * 8];
            float4 b1 = *(float4*)&Bs[kl][tx * 8 + 4];
            float av[8] = {a0.x, a0.y, a0.z, a0.w, a1.x, a1.y, a1.z, a1.w};
            float bv[8] = {b0.x, b0.y, b0.z, b0.w, b1.x, b1.y, b1.z, b1.w};
#pragma unroll
            for (int i2 = 0; i2 < 8; ++i2)
#pragma unroll
                for (int j2 = 0; j2 < 8; ++j2)
                    acc[i2][j2] = fmaf(av[i2], bv[j2], acc[i2][j2]);
        }
    }

    // epilogue: scaled write + fused per-row argmax (first-max tie-break preserved
    // via low word = 0xFFFFFFFF - q; larger packed = larger value or smaller q).
    size_t rowbase = ((size_t)b * THW + (size_t)tb * 128 + ty * 8) * HW + qb * 128 + tx * 8;
    int q0 = qb * 128 + tx * 8;
#pragma unroll
    for (int i = 0; i < 8; ++i) {
        float v[8];
#pragma unroll
        for (int j2 = 0; j2 < 8; ++j2) v[j2] = acc[i][j2] * SCALE;
        *(float4*)&p[rowbase + (size_t)i * HW]     = make_float4(v[0], v[1], v[2], v[3]);
        *(float4*)&p[rowbase + (size_t)i * HW + 4] = make_float4(v[4], v[5], v[6], v[7]);
        float best = v[0]; int bq = q0;
#pragma unroll
        for (int j2 = 1; j2 < 8; ++j2)
            if (v[j2] > best) { best = v[j2]; bq = q0 + j2; }
        unsigned long long pk = ((unsigned long long)ordf(best) << 32)
                              | (unsigned long long)(0xFFFFFFFFu - (unsigned)bq);
#pragma unroll
        for (int off = 1; off < 16; off <<= 1) {
            unsigned long long o = __shfl_xor(pk, off);
            if (o > pk) pk = o;
        }
        if ((lane & 15) == 0)
            atomicMax(&amax[(size_t)b * THW + (size_t)tb * 128 + ty * 8 + i], pk);
    }
}

// ---------------- online softmax stats over t (chunked): z = p - d2*INV2S2 ----------------
__global__ __launch_bounds__(256) void k_colstats(const float* __restrict__ p,
                                                  const unsigned long long* __restrict__ amax,
                                                  float* __restrict__ part)
{
    int q  = blockIdx.x * 256 + threadIdx.x;
    int ch = blockIdx.y, b = blockIdx.z;
    float x = (float)(q & 31), y = (float)(q >> 5);
    const float* pp = p + ((size_t)b * THW + ch * CHT) * HW + q;
    const unsigned long long* am = amax + (size_t)b * THW + ch * CHT;
    float m = -3.0e38f, s = 0.f;
    for (int i = 0; i < CHT; ++i) {
        unsigned idx = 0xFFFFFFFFu - (unsigned)am[i];
        float dx = x - (float)(idx & 31), dy = y - (float)(idx >> 5);
        float z = pp[(size_t)i * HW] - (dx * dx + dy * dy) * INV2S2;
        float nm = fmaxf(m, z);
        s = s * __expf(m - nm) + __expf(z - nm);
        m = nm;
    }
    size_t o = ((size_t)(b * NCH + ch) * HW + q) * 2;
    part[o] = m; part[o + 1] = s;
}

// ---------------- combine chunk partials -> (M, 1/S) per (b,q) ----------------
__global__ __launch_bounds__(256) void k_reduce(const float* __restrict__ part,
                                                float* __restrict__ stats)
{
    int i = blockIdx.x * 256 + threadIdx.x;
    int b = i >> 10, q = i & 1023;
    float M = -3.0e38f;
#pragma unroll
    for (int c = 0; c < NCH; ++c)
        M = fmaxf(M, part[((size_t)(b * NCH + c) * HW + q) * 2]);
    float S = 0.f;
#pragma unroll
    for (int c = 0; c < NCH; ++c) {
        size_t o = ((size_t)(b * NCH + c) * HW + q) * 2;
        S += part[o + 1] * __expf(part[o] - M);
    }
    stats[(size_t)i * 2] = M;
    stats[(size_t)i * 2 + 1] = 1.0f / S;
}

// ---------------- p_w fp32 (in place) + bf16 transposed copy pwT[b][q][t] ----------------
__global__ __launch_bounds__(256) void k_pwt(float* __restrict__ p,
                                             const unsigned long long* __restrict__ amax,
                                             const float* __restrict__ stats,
                                             unsigned short* __restrict__ pwT)
{
    __shared__ float tile[64][65];
    __shared__ float ctr[128];    // 64 x (cx, cy)
    __shared__ float st[128];     // 64 x (M, invS)
    int qb = blockIdx.x, tb = blockIdx.y, b = blockIdx.z;
    int tid = threadIdx.x;
    if (tid < 64) {
        unsigned idx = 0xFFFFFFFFu - (unsigned)amax[(size_t)b * THW + tb * 64 + tid];
        ctr[tid * 2]     = (float)(idx & 31);
        ctr[tid * 2 + 1] = (float)(idx >> 5);
    }
    if (tid < 128)
        st[tid] = stats[((size_t)b * HW + qb * 64) * 2 + tid];
    __syncthreads();
    // phase A: pw = exp(p - d2*INV2S2 - M) * invS; write fp32, stash in LDS
    int r0 = tid >> 4;
    int c4 = (tid & 15) << 2;
#pragma unroll
    for (int i = 0; i < 4; ++i) {
        int r = r0 + i * 16;                       // t-local
        float* pp = p + ((size_t)b * THW + tb * 64 + r) * HW + qb * 64 + c4;
        float4 v = *(float4*)pp;
        float cx = ctr[r * 2], cy = ctr[r * 2 + 1];
        float vv[4] = {v.x, v.y, v.z, v.w};
#pragma unroll
        for (int j = 0; j < 4; ++j) {
            int q = qb * 64 + c4 + j;
            float x = (float)(q & 31), y = (float)(q >> 5);
            float dx = x - cx, dy = y - cy;
            vv[j] = __expf(vv[j] - (dx * dx + dy * dy) * INV2S2 - st[(c4 + j) * 2])
                    * st[(c4 + j) * 2 + 1];
            tile[r][c4 + j] = vv[j];
        }
        *(float4*)pp = make_float4(vv[0], vv[1], vv[2], vv[3]);
    }
    __syncthreads();
    // phase B: transposed bf16 write (row = q-local, 64 t contiguous)
    int ql = tid >> 3;
    int t0 = (tid & 7) << 3;
#pragma unroll
    for (int pass = 0; pass < 2; ++pass) {
        int q = ql + pass * 32;
        u16x8 o8;
#pragma unroll
        for (int j = 0; j < 8; ++j)
            o8[j] = f2bf(tile[t0 + j][q]);
        *(u16x8*)&pwT[((size_t)b * HW + qb * 64 + q) * THW + tb * 64 + t0] = o8;
    }
}

// ---------------- mo fp32 -> bf16 ----------------
__global__ __launch_bounds__(256) void k_mo16(const float* __restrict__ mo,
                                              unsigned short* __restrict__ o)
{
    size_t base = ((size_t)blockIdx.x * 256 + threadIdx.x) * 8;
    float4 a = *(const float4*)(mo + base);
    float4 c = *(const float4*)(mo + base + 4);
    u16x8 v;
    v[0] = f2bf(a.x); v[1] = f2bf(a.y); v[2] = f2bf(a.z); v[3] = f2bf(a.w);
    v[4] = f2bf(c.x); v[5] = f2bf(c.y); v[6] = f2bf(c.z); v[7] = f2bf(c.w);
    *(u16x8*)(o + base) = v;
}

// ---------------- GEMM2 (MFMA bf16): mem[b][d][q] += sum_t mo16[b][d][t]*pwT[b][q][t] ----------------
// 128x128 tile, BK=32, 4-way K-split (atomics), global_load_lds staging with
// XOR(k-group, row&3) swizzle. 16x mfma_f32_16x16x32_bf16 + 8x ds_read_b128/iter.
// XCD slice swizzle: 1D grid 512, id%8 constant per (b,ks) slice → each slice's
// 32 blocks (8 nb x 4 mb, sharing A and B panels) land on one XCD → A/B fetched
// once from HBM (~126 MB compulsory, was ~420 MB with nb as the fast dim).
__global__ __launch_bounds__(256) void k_gemm2m(const unsigned short* __restrict__ A16,
                                                const unsigned short* __restrict__ B16,
                                                float* __restrict__ out)
{
    __shared__ unsigned short As[4096];   // [128][32] bf16; 16B-group g at slot g^(row&3)
    __shared__ unsigned short Bs[4096];
    int id   = blockIdx.x;
    int xcd  = id & 7;
    int rest = id >> 3;            // [0,64)
    int shi  = rest >> 5;          // [0,2)
    int jj   = rest & 31;          // [0,32)
    int s    = xcd + (shi << 3);   // slice [0,16)
    int b    = s >> 2, ks = s & 3;
    int mb   = jj >> 3, nb = jj & 7;
    int tid = threadIdx.x;
    int w = tid >> 6, lane = tid & 63;
    int quad = lane >> 4, l15 = lane & 15;

    const char* Ag = (const char*)(A16 + (size_t)b * DO_ * THW + (size_t)mb * 128 * THW + ks * 2560);
    const char* Bg = (const char*)(B16 + (size_t)b * HW * THW + (size_t)nb * 128 * THW + ks * 2560);

    int srow = lane >> 2;                    // row within 16-row staging chunk
    int sj   = (lane & 3) ^ (srow & 3);      // swizzled k-group this lane fetches
    const char* aP0 = Ag + (size_t)((w * 2 + 0) * 16 + srow) * (THW * 2) + sj * 16;
    const char* aP1 = Ag + (size_t)((w * 2 + 1) * 16 + srow) * (THW * 2) + sj * 16;
    const char* bP0 = Bg + (size_t)((w * 2 + 0) * 16 + srow) * (THW * 2) + sj * 16;
    const char* bP1 = Bg + (size_t)((w * 2 + 1) * 16 + srow) * (THW * 2) + sj * 16;
    char* lA0 = (char*)As + (w * 2 + 0) * 1024;
    char* lA1 = (char*)As + (w * 2 + 1) * 1024;
    char* lB0 = (char*)Bs + (w * 2 + 0) * 1024;
    char* lB1 = (char*)Bs + (w * 2 + 1) * 1024;

    int wm = w >> 1, wn = w & 1;
    int fq = ((l15 & 3) ^ quad) << 4;        // swizzled frag k-group offset
    const char* aF = (const char*)As + (wm * 64 + l15) * 64 + fq;
    const char* bF = (const char*)Bs + (wn * 64 + l15) * 64 + fq;

    f32x4 acc[4][4];
#pragma unroll
    for (int i = 0; i < 4; ++i)
#pragma unroll
        for (int j = 0; j < 4; ++j)
            acc[i][j] = (f32x4){0.f, 0.f, 0.f, 0.f};

    for (int kit = 0; kit < 80; ++kit) {
        int kb = kit * 64;
        __syncthreads();
        glds16(aP0 + kb, lA0);
        glds16(aP1 + kb, lA1);
        glds16(bP0 + kb, lB0);
        glds16(bP1 + kb, lB1);
        __syncthreads();
        bf16x8 af[4], bfr[4];
#pragma unroll
        for (int i = 0; i < 4; ++i) af[i]  = *(const bf16x8*)(aF + i * 1024);
#pragma unroll
        for (int j = 0; j < 4; ++j) bfr[j] = *(const bf16x8*)(bF + j * 1024);
#pragma unroll
        for (int i = 0; i < 4; ++i)
#pragma unroll
            for (int j = 0; j < 4; ++j)
                acc[i][j] = __builtin_amdgcn_mfma_f32_16x16x32_bf16(af[i], bfr[j], acc[i][j], 0, 0, 0);
    }

    float* Cg = out + (size_t)b * (2 * DO_ * HW);
    int d0 = mb * 128 + wm * 64 + quad * 4;
    int q0 = nb * 128 + wn * 64 + l15;
#pragma unroll
    for (int i = 0; i < 4; ++i)
#pragma unroll
        for (int j = 0; j < 4; ++j)
#pragma unroll
            for (int r = 0; r < 4; ++r)
                atomicAdd(&Cg[(size_t)(d0 + i * 16 + r) * HW + q0 + j * 16], acc[i][j][r]);
}

extern "C" void kernel_launch(void* const* d_in, const int* in_sizes, int n_in,
                              void* d_out, int out_size, void* d_ws, size_t ws_size,
                              hipStream_t stream)
{
    const float* m_in  = (const float*)d_in[0];
    const float* m_out = (const float*)d_in[1];
    const float* q_in  = (const float*)d_in[2];
    const float* q_out = (const float*)d_in[3];
    float* out = (float*)d_out;
    float* pw  = out + (size_t)BB * 2 * DO_ * HW;   // p / p_w region of d_out (in place)
    float* ws  = (float*)d_ws;
    unsigned long long* amax = (unsigned long long*)d_ws;
    float* part    = ws + WS_PART_F;
    float* stats   = ws + WS_STATS_F;
    unsigned short* mo16  = (unsigned short*)((char*)d_ws + WS_MO16_B);
    unsigned short* pwT16 = (unsigned short*)((char*)d_ws + WS_PWT_B);

    hipLaunchKernelGGL(k_init,    dim3(4096),        dim3(256), 0, stream, out, q_out, (float4*)d_ws);
    hipLaunchKernelGGL(k_mo16,    dim3(10240),       dim3(256), 0, stream, m_out, mo16);
    hipLaunchKernelGGL(k_gemm1,   dim3(2560),        dim3(256), 0, stream, m_in, q_in, pw, amax);
    hipLaunchKernelGGL(k_colstats,dim3(4, NCH, BB),  dim3(256), 0, stream, pw, amax, part);
    hipLaunchKernelGGL(k_reduce,  dim3(16),          dim3(256), 0, stream, part, stats);
    hipLaunchKernelGGL(k_pwt,     dim3(16, 160, BB), dim3(256), 0, stream, pw, amax, stats, pwT16);
    hipLaunchKernelGGL(k_gemm2m,  dim3(512),         dim3(256), 0, stream, mo16, pwT16, out);
}

// Round 2
// 516.807 us; speedup vs baseline: 1.1152x; 1.1152x over previous
//
#include <hip/hip_runtime.h>
#include <hip/hip_bf16.h>

#define BB 4
#define DE 128
#define DO_ 512
#define THW 10240
#define HW 1024
#define SCALE 0.08838834764831845f      // 1/sqrt(128)
#define INV2S2 0.05555555555555555f     // 1/(2*3^2)
#define NCH 32
#define CHT 320                          // 10240 / 32

// ws layout (bytes):
//   amax  @ 0          : BB*THW ull packed (value,~idx) argmax   (327,680 B)
//   part  @ 327,680    : BB*NCH*HW*2 floats                      (1,048,576 B)
//   stats @ 1,376,256  : BB*HW*2 floats                          (32,768 B)
//   mo16  @ 1,409,024  : bf16 mo   [B][Do][THW]                  (41.94 MB)
//   pwT   @ 43,352,064 : bf16 pw^T [B][HW][THW]                  (83.89 MB)
// The pwT region doubles (before k_pwt runs) as scratch for the f16-split
// transposed gemm1 operands: miT_H/L [B][THW][128] f16 (10.49 MB each),
// qiT_H/L [B][HW][128] f16 (1.05 MB each) = 23.07 MB < 83.89 MB.
// Total ws requirement: 127,238,144 bytes (~121.3 MiB) — unchanged.
#define WS_PART_F  81920
#define WS_STATS_F 344064
#define WS_MO16_B  1409024ull
#define WS_PWT_B   43352064ull
#define WS_MITH_B  (WS_PWT_B)
#define WS_MITL_B  (WS_PWT_B + 10485760ull)
#define WS_QITH_B  (WS_PWT_B + 20971520ull)
#define WS_QITL_B  (WS_PWT_B + 22020096ull)

using bf16x8 = __attribute__((ext_vector_type(8))) short;
using f16x8  = __attribute__((ext_vector_type(8))) _Float16;
using f32x4  = __attribute__((ext_vector_type(4))) float;
using u16x8  = __attribute__((ext_vector_type(8))) unsigned short;

__device__ __forceinline__ unsigned short f2bf(float f) {
    __hip_bfloat16 h = __float2bfloat16(f);
    return *reinterpret_cast<unsigned short*>(&h);
}
__device__ __forceinline__ void glds16(const void* g, void* l) {
    __builtin_amdgcn_global_load_lds((const __attribute__((address_space(1))) void*)g,
                                     (__attribute__((address_space(3))) void*)l,
                                     16, 0, 0);
}
// monotone float->uint mapping (order-preserving for all finite floats)
__device__ __forceinline__ unsigned int ordf(float f) {
    unsigned int u = __float_as_uint(f);
    return (u & 0x80000000u) ? ~u : (u | 0x80000000u);
}

// ---------------- init: zero mem part of out, copy q_out part, zero amax ----------------
__global__ __launch_bounds__(256) void k_init(float* __restrict__ out,
                                              const float* __restrict__ qout,
                                              float4* __restrict__ amax4)
{
    int idx = blockIdx.x * 256 + threadIdx.x;
    if (idx < 20480) amax4[idx] = make_float4(0.f, 0.f, 0.f, 0.f);  // 327,680 B of amax
    int b  = idx >> 18;
    int r  = idx & 262143;
    int c  = r >> 8;
    int q4 = r & 255;
    float4* dst = (float4*)out + idx;
    if (c < DO_) {
        *dst = make_float4(0.f, 0.f, 0.f, 0.f);
    } else {
        const float4* src = (const float4*)qout + ((size_t)(b * DO_ + (c - DO_)) << 8) + q4;
        *dst = *src;
    }
}

// ---------------- split+transpose: src [B][128][ncols] fp32 -> hi/lo f16 [B][ncols][128] ----------------
// hi = f16(v*scale); lo = f16((v*scale - hi) * 2^11)   (2^11 keeps lo normal in f16)
__global__ __launch_bounds__(256) void k_split(const float* __restrict__ src,
                                               unsigned short* __restrict__ dstH,
                                               unsigned short* __restrict__ dstL,
                                               int ncols, float scale)
{
    __shared__ float tile[128][65];
    int t0 = blockIdx.x * 64;
    int b  = blockIdx.z;
    int tid = threadIdx.x;
    const float* S = src + (size_t)b * DE * ncols + t0;
#pragma unroll
    for (int i = 0; i < 8; ++i) {
        int s  = tid + i * 256;
        int k  = s >> 4;
        int c4 = (s & 15) << 2;
        *(float4*)&tile[k][c4] = *(const float4*)&S[(size_t)k * ncols + c4];
    }
    __syncthreads();
#pragma unroll
    for (int i = 0; i < 4; ++i) {
        int s  = tid + i * 256;
        int t  = s >> 4;          // 0..63
        int k8 = s & 15;          // 0..15
        u16x8 oh, ol;
#pragma unroll
        for (int j = 0; j < 8; ++j) {
            float v = tile[k8 * 8 + j][t] * scale;
            _Float16 h = (_Float16)v;
            float rr = v - (float)h;
            _Float16 l = (_Float16)(rr * 2048.0f);
            oh[j] = *(unsigned short*)&h;
            ol[j] = *(unsigned short*)&l;
        }
        size_t o = ((size_t)b * ncols + t0 + t) * 128 + k8 * 8;
        *(u16x8*)&dstH[o] = oh;
        *(u16x8*)&dstL[o] = ol;
    }
}

// ---------------- GEMM1 (MFMA f16x3) + fused row argmax ----------------
// p[t][q] = sum_k miT[t][k]*qiT[q][k]  (qiT pre-scaled by 1/sqrt(128)).
// f16 split: p = acc1(H*H) + 2^-11 * acc2(H*L + L*H); per-element error ~2^-23 rel,
// same class as fp32 reassociation -> argmax preserved (w.h.p. on fixed data).
// 128x128 tile, BK=32, glds16 staging with XOR(k-group,row&3) swizzle (gemm2m pattern).
// XCD slice swizzle: id%8 = tb-group -> A panels L2-local per XCD.
__global__ __launch_bounds__(256) void k_gemm1m(const unsigned short* __restrict__ AH,
                                                const unsigned short* __restrict__ AL,
                                                const unsigned short* __restrict__ BH,
                                                const unsigned short* __restrict__ BL,
                                                float* __restrict__ p,
                                                unsigned long long* __restrict__ amax)
{
    __shared__ unsigned short AsH[4096];  // [128][32] f16; 16B-group g at slot g^(row&3)
    __shared__ unsigned short AsL[4096];
    __shared__ unsigned short BsH[4096];
    __shared__ unsigned short BsL[4096];
    int id  = blockIdx.x;
    int tbg = id & 7;
    int rr  = id >> 3;              // [0,320)
    int b   = rr / 80;
    int j   = rr - b * 80;          // [0,80)
    int tb  = tbg * 10 + (j >> 3);  // [0,80)
    int qb  = j & 7;                // [0,8)
    int tid = threadIdx.x;
    int w = tid >> 6, lane = tid & 63;
    int quad = lane >> 4, l15 = lane & 15;

    const char* AgH = (const char*)AH + ((size_t)b * THW + (size_t)tb * 128) * 256;
    const char* AgL = (const char*)AL + ((size_t)b * THW + (size_t)tb * 128) * 256;
    const char* BgH = (const char*)BH + ((size_t)b * HW + qb * 128) * 256;
    const char* BgL = (const char*)BL + ((size_t)b * HW + qb * 128) * 256;

    int srow = lane >> 2;                    // row within 16-row staging chunk
    int sj   = (lane & 3) ^ (srow & 3);      // swizzled k-group this lane fetches
    size_t ro0 = (size_t)(w * 32 + srow) * 256 + sj * 16;
    size_t ro1 = (size_t)(w * 32 + 16 + srow) * 256 + sj * 16;
    char* lds0[4] = {(char*)AsH + w * 2048, (char*)AsL + w * 2048,
                     (char*)BsH + w * 2048, (char*)BsL + w * 2048};
    const char* gl0[4] = {AgH, AgL, BgH, BgL};

    int wm = w >> 1, wn = w & 1;
    int fq = ((l15 & 3) ^ quad) << 4;        // swizzled frag k-group offset
    const char* aFH = (const char*)AsH + (wm * 64 + l15) * 64 + fq;
    const char* aFL = (const char*)AsL + (wm * 64 + l15) * 64 + fq;
    const char* bFH = (const char*)BsH + (wn * 64 + l15) * 64 + fq;
    const char* bFL = (const char*)BsL + (wn * 64 + l15) * 64 + fq;

    f32x4 acc1[4][4], acc2[4][4];
#pragma unroll
    for (int i = 0; i < 4; ++i)
#pragma unroll
        for (int j2 = 0; j2 < 4; ++j2) {
            acc1[i][j2] = (f32x4){0.f, 0.f, 0.f, 0.f};
            acc2[i][j2] = (f32x4){0.f, 0.f, 0.f, 0.f};
        }

    for (int kc = 0; kc < 4; ++kc) {
        size_t kb = (size_t)kc * 64;
        __syncthreads();
#pragma unroll
        for (int m = 0; m < 4; ++m) {
            glds16(gl0[m] + ro0 + kb, lds0[m]);
            glds16(gl0[m] + ro1 + kb, lds0[m] + 1024);
        }
        __syncthreads();
        f16x8 afH[4], afL[4], bfH[4], bfL[4];
#pragma unroll
        for (int i = 0; i < 4; ++i) {
            afH[i] = *(const f16x8*)(aFH + i * 1024);
            afL[i] = *(const f16x8*)(aFL + i * 1024);
            bfH[i] = *(const f16x8*)(bFH + i * 1024);
            bfL[i] = *(const f16x8*)(bFL + i * 1024);
        }
#pragma unroll
        for (int i = 0; i < 4; ++i)
#pragma unroll
            for (int j2 = 0; j2 < 4; ++j2)
                acc1[i][j2] = __builtin_amdgcn_mfma_f32_16x16x32_f16(afH[i], bfH[j2], acc1[i][j2], 0, 0, 0);
#pragma unroll
        for (int i = 0; i < 4; ++i)
#pragma unroll
            for (int j2 = 0; j2 < 4; ++j2)
                acc2[i][j2] = __builtin_amdgcn_mfma_f32_16x16x32_f16(afH[i], bfL[j2], acc2[i][j2], 0, 0, 0);
#pragma unroll
        for (int i = 0; i < 4; ++i)
#pragma unroll
            for (int j2 = 0; j2 < 4; ++j2)
                acc2[i][j2] = __builtin_amdgcn_mfma_f32_16x16x32_f16(afL[i], bfH[j2], acc2[i][j2], 0, 0, 0);
    }

    // epilogue: p store + fused per-row argmax (first-max tie-break via ~q low word)
    const float inv2048 = 4.8828125e-4f;
    int t0 = tb * 128 + wm * 64;
    float* Pg = p + ((size_t)b * THW + t0) * HW + qb * 128 + wn * 64;
    int qbase = qb * 128 + wn * 64;
#pragma unroll
    for (int i = 0; i < 4; ++i) {
#pragma unroll
        for (int r = 0; r < 4; ++r) {
            int tl = i * 16 + quad * 4 + r;   // wave-local row
            float v[4];
#pragma unroll
            for (int j2 = 0; j2 < 4; ++j2) {
                v[j2] = acc1[i][j2][r] + acc2[i][j2][r] * inv2048;
                Pg[(size_t)tl * HW + j2 * 16 + l15] = v[j2];
            }
            float best = v[0]; int bj = 0;
#pragma unroll
            for (int j2 = 1; j2 < 4; ++j2)
                if (v[j2] > best) { best = v[j2]; bj = j2; }
            int q = qbase + bj * 16 + l15;
            unsigned long long pk = ((unsigned long long)ordf(best) << 32)
                                  | (unsigned long long)(0xFFFFFFFFu - (unsigned)q);
#pragma unroll
            for (int off = 1; off < 16; off <<= 1) {
                unsigned long long o = __shfl_xor(pk, off);
                if (o > pk) pk = o;
            }
            if (l15 == 0)
                atomicMax(&amax[(size_t)b * THW + t0 + tl], pk);
        }
    }
}

// ---------------- online softmax stats over t (chunked): z = p - d2*INV2S2 ----------------
__global__ __launch_bounds__(256) void k_colstats(const float* __restrict__ p,
                                                  const unsigned long long* __restrict__ amax,
                                                  float* __restrict__ part)
{
    int q  = blockIdx.x * 256 + threadIdx.x;
    int ch = blockIdx.y, b = blockIdx.z;
    float x = (float)(q & 31), y = (float)(q >> 5);
    const float* pp = p + ((size_t)b * THW + ch * CHT) * HW + q;
    const unsigned long long* am = amax + (size_t)b * THW + ch * CHT;
    float m = -3.0e38f, s = 0.f;
    for (int i = 0; i < CHT; ++i) {
        unsigned idx = 0xFFFFFFFFu - (unsigned)am[i];
        float dx = x - (float)(idx & 31), dy = y - (float)(idx >> 5);
        float z = pp[(size_t)i * HW] - (dx * dx + dy * dy) * INV2S2;
        float nm = fmaxf(m, z);
        s = s * __expf(m - nm) + __expf(z - nm);
        m = nm;
    }
    size_t o = ((size_t)(b * NCH + ch) * HW + q) * 2;
    part[o] = m; part[o + 1] = s;
}

// ---------------- combine chunk partials -> (M, 1/S) per (b,q) ----------------
__global__ __launch_bounds__(256) void k_reduce(const float* __restrict__ part,
                                                float* __restrict__ stats)
{
    int i = blockIdx.x * 256 + threadIdx.x;
    int b = i >> 10, q = i & 1023;
    float M = -3.0e38f;
#pragma unroll
    for (int c = 0; c < NCH; ++c)
        M = fmaxf(M, part[((size_t)(b * NCH + c) * HW + q) * 2]);
    float S = 0.f;
#pragma unroll
    for (int c = 0; c < NCH; ++c) {
        size_t o = ((size_t)(b * NCH + c) * HW + q) * 2;
        S += part[o + 1] * __expf(part[o] - M);
    }
    stats[(size_t)i * 2] = M;
    stats[(size_t)i * 2 + 1] = 1.0f / S;
}

// ---------------- p_w fp32 (in place) + bf16 transposed copy pwT[b][q][t] ----------------
__global__ __launch_bounds__(256) void k_pwt(float* __restrict__ p,
                                             const unsigned long long* __restrict__ amax,
                                             const float* __restrict__ stats,
                                             unsigned short* __restrict__ pwT)
{
    __shared__ float tile[64][65];
    __shared__ float ctr[128];    // 64 x (cx, cy)
    __shared__ float st[128];     // 64 x (M, invS)
    int qb = blockIdx.x, tb = blockIdx.y, b = blockIdx.z;
    int tid = threadIdx.x;
    if (tid < 64) {
        unsigned idx = 0xFFFFFFFFu - (unsigned)amax[(size_t)b * THW + tb * 64 + tid];
        ctr[tid * 2]     = (float)(idx & 31);
        ctr[tid * 2 + 1] = (float)(idx >> 5);
    }
    if (tid < 128)
        st[tid] = stats[((size_t)b * HW + qb * 64) * 2 + tid];
    __syncthreads();
    // phase A: pw = exp(p - d2*INV2S2 - M) * invS; write fp32, stash in LDS
    int r0 = tid >> 4;
    int c4 = (tid & 15) << 2;
#pragma unroll
    for (int i = 0; i < 4; ++i) {
        int r = r0 + i * 16;                       // t-local
        float* pp = p + ((size_t)b * THW + tb * 64 + r) * HW + qb * 64 + c4;
        float4 v = *(float4*)pp;
        float cx = ctr[r * 2], cy = ctr[r * 2 + 1];
        float vv[4] = {v.x, v.y, v.z, v.w};
#pragma unroll
        for (int j = 0; j < 4; ++j) {
            int q = qb * 64 + c4 + j;
            float x = (float)(q & 31), y = (float)(q >> 5);
            float dx = x - cx, dy = y - cy;
            vv[j] = __expf(vv[j] - (dx * dx + dy * dy) * INV2S2 - st[(c4 + j) * 2])
                    * st[(c4 + j) * 2 + 1];
            tile[r][c4 + j] = vv[j];
        }
        *(float4*)pp = make_float4(vv[0], vv[1], vv[2], vv[3]);
    }
    __syncthreads();
    // phase B: transposed bf16 write (row = q-local, 64 t contiguous)
    int ql = tid >> 3;
    int t0 = (tid & 7) << 3;
#pragma unroll
    for (int pass = 0; pass < 2; ++pass) {
        int q = ql + pass * 32;
        u16x8 o8;
#pragma unroll
        for (int j = 0; j < 8; ++j)
            o8[j] = f2bf(tile[t0 + j][q]);
        *(u16x8*)&pwT[((size_t)b * HW + qb * 64 + q) * THW + tb * 64 + t0] = o8;
    }
}

// ---------------- mo fp32 -> bf16 ----------------
__global__ __launch_bounds__(256) void k_mo16(const float* __restrict__ mo,
                                              unsigned short* __restrict__ o)
{
    size_t base = ((size_t)blockIdx.x * 256 + threadIdx.x) * 8;
    float4 a = *(const float4*)(mo + base);
    float4 c = *(const float4*)(mo + base + 4);
    u16x8 v;
    v[0] = f2bf(a.x); v[1] = f2bf(a.y); v[2] = f2bf(a.z); v[3] = f2bf(a.w);
    v[4] = f2bf(c.x); v[5] = f2bf(c.y); v[6] = f2bf(c.z); v[7] = f2bf(c.w);
    *(u16x8*)(o + base) = v;
}

// ---------------- GEMM2 (MFMA bf16): mem[b][d][q] += sum_t mo16[b][d][t]*pwT[b][q][t] ----------------
// 128x128 tile, BK=32, 4-way K-split (atomics), global_load_lds staging with
// XOR(k-group, row&3) swizzle. 16x mfma_f32_16x16x32_bf16 + 8x ds_read_b128/iter.
// XCD slice swizzle: 1D grid 512, id%8 constant per (b,ks) slice → each slice's
// 32 blocks (8 nb x 4 mb, sharing A and B panels) land on one XCD → A/B fetched
// once from HBM (~126 MB compulsory, was ~420 MB with nb as the fast dim).
__global__ __launch_bounds__(256) void k_gemm2m(const unsigned short* __restrict__ A16,
                                                const unsigned short* __restrict__ B16,
                                                float* __restrict__ out)
{
    __shared__ unsigned short As[4096];   // [128][32] bf16; 16B-group g at slot g^(row&3)
    __shared__ unsigned short Bs[4096];
    int id   = blockIdx.x;
    int xcd  = id & 7;
    int rest = id >> 3;            // [0,64)
    int shi  = rest >> 5;          // [0,2)
    int jj   = rest & 31;          // [0,32)
    int s    = xcd + (shi << 3);   // slice [0,16)
    int b    = s >> 2, ks = s & 3;
    int mb   = jj >> 3, nb = jj & 7;
    int tid = threadIdx.x;
    int w = tid >> 6, lane = tid & 63;
    int quad = lane >> 4, l15 = lane & 15;

    const char* Ag = (const char*)(A16 + (size_t)b * DO_ * THW + (size_t)mb * 128 * THW + ks * 2560);
    const char* Bg = (const char*)(B16 + (size_t)b * HW * THW + (size_t)nb * 128 * THW + ks * 2560);

    int srow = lane >> 2;                    // row within 16-row staging chunk
    int sj   = (lane & 3) ^ (srow & 3);      // swizzled k-group this lane fetches
    const char* aP0 = Ag + (size_t)((w * 2 + 0) * 16 + srow) * (THW * 2) + sj * 16;
    const char* aP1 = Ag + (size_t)((w * 2 + 1) * 16 + srow) * (THW * 2) + sj * 16;
    const char* bP0 = Bg + (size_t)((w * 2 + 0) * 16 + srow) * (THW * 2) + sj * 16;
    const char* bP1 = Bg + (size_t)((w * 2 + 1) * 16 + srow) * (THW * 2) + sj * 16;
    char* lA0 = (char*)As + (w * 2 + 0) * 1024;
    char* lA1 = (char*)As + (w * 2 + 1) * 1024;
    char* lB0 = (char*)Bs + (w * 2 + 0) * 1024;
    char* lB1 = (char*)Bs + (w * 2 + 1) * 1024;

    int wm = w >> 1, wn = w & 1;
    int fq = ((l15 & 3) ^ quad) << 4;        // swizzled frag k-group offset
    const char* aF = (const char*)As + (wm * 64 + l15) * 64 + fq;
    const char* bF = (const char*)Bs + (wn * 64 + l15) * 64 + fq;

    f32x4 acc[4][4];
#pragma unroll
    for (int i = 0; i < 4; ++i)
#pragma unroll
        for (int j = 0; j < 4; ++j)
            acc[i][j] = (f32x4){0.f, 0.f, 0.f, 0.f};

    for (int kit = 0; kit < 80; ++kit) {
        int kb = kit * 64;
        __syncthreads();
        glds16(aP0 + kb, lA0);
        glds16(aP1 + kb, lA1);
        glds16(bP0 + kb, lB0);
        glds16(bP1 + kb, lB1);
        __syncthreads();
        bf16x8 af[4], bfr[4];
#pragma unroll
        for (int i = 0; i < 4; ++i) af[i]  = *(const bf16x8*)(aF + i * 1024);
#pragma unroll
        for (int j = 0; j < 4; ++j) bfr[j] = *(const bf16x8*)(bF + j * 1024);
#pragma unroll
        for (int i = 0; i < 4; ++i)
#pragma unroll
            for (int j = 0; j < 4; ++j)
                acc[i][j] = __builtin_amdgcn_mfma_f32_16x16x32_bf16(af[i], bfr[j], acc[i][j], 0, 0, 0);
    }

    float* Cg = out + (size_t)b * (2 * DO_ * HW);
    int d0 = mb * 128 + wm * 64 + quad * 4;
    int q0 = nb * 128 + wn * 64 + l15;
#pragma unroll
    for (int i = 0; i < 4; ++i)
#pragma unroll
        for (int j = 0; j < 4; ++j)
#pragma unroll
            for (int r = 0; r < 4; ++r)
                atomicAdd(&Cg[(size_t)(d0 + i * 16 + r) * HW + q0 + j * 16], acc[i][j][r]);
}

extern "C" void kernel_launch(void* const* d_in, const int* in_sizes, int n_in,
                              void* d_out, int out_size, void* d_ws, size_t ws_size,
                              hipStream_t stream)
{
    const float* m_in  = (const float*)d_in[0];
    const float* m_out = (const float*)d_in[1];
    const float* q_in  = (const float*)d_in[2];
    const float* q_out = (const float*)d_in[3];
    float* out = (float*)d_out;
    float* pw  = out + (size_t)BB * 2 * DO_ * HW;   // p / p_w region of d_out (in place)
    float* ws  = (float*)d_ws;
    unsigned long long* amax = (unsigned long long*)d_ws;
    float* part    = ws + WS_PART_F;
    float* stats   = ws + WS_STATS_F;
    unsigned short* mo16  = (unsigned short*)((char*)d_ws + WS_MO16_B);
    unsigned short* pwT16 = (unsigned short*)((char*)d_ws + WS_PWT_B);
    unsigned short* miTH  = (unsigned short*)((char*)d_ws + WS_MITH_B);
    unsigned short* miTL  = (unsigned short*)((char*)d_ws + WS_MITL_B);
    unsigned short* qiTH  = (unsigned short*)((char*)d_ws + WS_QITH_B);
    unsigned short* qiTL  = (unsigned short*)((char*)d_ws + WS_QITL_B);

    hipLaunchKernelGGL(k_init,    dim3(4096),        dim3(256), 0, stream, out, q_out, (float4*)d_ws);
    hipLaunchKernelGGL(k_split,   dim3(160, 1, BB),  dim3(256), 0, stream, m_in, miTH, miTL, THW, 1.0f);
    hipLaunchKernelGGL(k_split,   dim3(16, 1, BB),   dim3(256), 0, stream, q_in, qiTH, qiTL, HW, SCALE);
    hipLaunchKernelGGL(k_gemm1m,  dim3(2560),        dim3(256), 0, stream, miTH, miTL, qiTH, qiTL, pw, amax);
    hipLaunchKernelGGL(k_colstats,dim3(4, NCH, BB),  dim3(256), 0, stream, pw, amax, part);
    hipLaunchKernelGGL(k_reduce,  dim3(16),          dim3(256), 0, stream, part, stats);
    hipLaunchKernelGGL(k_mo16,    dim3(10240),       dim3(256), 0, stream, m_out, mo16);
    hipLaunchKernelGGL(k_pwt,     dim3(16, 160, BB), dim3(256), 0, stream, pw, amax, stats, pwT16);
    hipLaunchKernelGGL(k_gemm2m,  dim3(512),         dim3(256), 0, stream, mo16, pwT16, out);
}